// Round 3
// baseline (3116.497 us; speedup 1.0000x reference)
//
#include <hip/hip_runtime.h>
#include <math.h>

// NaryTreeLSTM on MI355X — round 3: fused GEMM+epilogue, pre never hits HBM.
// DEPTH=16, HID=INP=256, K=2, TOTAL=131071.
//
// Internal level d (n=2^d): Z=[xs|Hs] (n x 512 bf16), pre = Z@Wbig^T + bbig,
//   Wbig rows: [0:256)=[Wi|Ui],[256:512)=[Wo|Uo],[512:768)=[Wu|Uu],
//              [768:1024)=[Wf|Wfk0],[1024:1280)=[Wf|Wfk1]
//   c = sig(i)*tanh(u) + sig(f0)*c0 + sig(f1)*c1; h = sig(o)*tanh(c)
//   Epilogue writes c (fp32) and Hs=h(2j)+h(2j+1) (bf16) into parent Z.
// Leaf: pre = xbf @ [Wi;Wo;Wu]^T + b; c=sig(i)*tanh(u); h=sig(o)*tanh(c).
// Fused path for n>=2048 + leaf; unfused (gemm+epi_small) for n<=1024.

#define LEAF_N   65536
#define LEAF_ST  65535

typedef __attribute__((ext_vector_type(8))) short bf16x8;
typedef __attribute__((ext_vector_type(4))) float f32x4;

__device__ __forceinline__ float sigf(float x) { return 1.0f / (1.0f + expf(-x)); }

__device__ __forceinline__ unsigned short f2bf(float f) {
    union { float f; unsigned u; } v; v.f = f;
    unsigned r = v.u + 0x7fffu + ((v.u >> 16) & 1u);   // RNE
    return (unsigned short)(r >> 16);
}

// ---------------- weight packing (fp32 -> bf16) ----------------
__global__ __launch_bounds__(256) void pack_weights(
    const float* __restrict__ Wi, const float* __restrict__ bi,
    const float* __restrict__ Wf, const float* __restrict__ bf,
    const float* __restrict__ Wo, const float* __restrict__ bo,
    const float* __restrict__ Wu, const float* __restrict__ bu,
    const float* __restrict__ Ui, const float* __restrict__ Uo,
    const float* __restrict__ Uu, const float* __restrict__ Wfk,
    unsigned short* __restrict__ Wbig, unsigned short* __restrict__ Wleaf,
    float* __restrict__ bbig, float* __restrict__ bleaf)
{
    int idx = blockIdx.x * 256 + threadIdx.x;
    const int NWB = 1280 * 512;
    const int NWL = 768 * 256;
    if (idx < NWB) {
        int r = idx >> 9, k = idx & 511;
        int g = r >> 8, rr = r & 255;
        float v;
        if (k < 256) {
            const float* W = (g == 0) ? Wi : (g == 1) ? Wo : (g == 2) ? Wu : Wf;
            v = W[rr * 256 + k];
        } else {
            int kk = k - 256;
            v = (g == 0) ? Ui[rr * 256 + kk]
              : (g == 1) ? Uo[rr * 256 + kk]
              : (g == 2) ? Uu[rr * 256 + kk]
              : (g == 3) ? Wfk[rr * 256 + kk]
                         : Wfk[65536 + rr * 256 + kk];
        }
        Wbig[idx] = f2bf(v);
    } else if (idx < NWB + NWL) {
        int j = idx - NWB;
        int r = j >> 8, k = j & 255;
        int g = r >> 8, rr = r & 255;
        const float* W = (g == 0) ? Wi : (g == 1) ? Wo : Wu;
        Wleaf[j] = f2bf(W[rr * 256 + k]);
    } else if (idx < NWB + NWL + 1280) {
        int r = idx - NWB - NWL;
        int g = r >> 8, rr = r & 255;
        bbig[r] = (g == 0) ? bi[rr] : (g == 1) ? bo[rr] : (g == 2) ? bu[rr] : bf[rr];
    } else if (idx < NWB + NWL + 1280 + 768) {
        int r = idx - NWB - NWL - 1280;
        int g = r >> 8, rr = r & 255;
        bleaf[r] = (g == 0) ? bi[rr] : (g == 1) ? bo[rr] : bu[rr];
    }
}

// ---------------- one-shot x conversion into all levels' Z (+ leaf Xbf) -----
// Zbuf level offset (elems): zoff(d) = (65536 - 2^(d+1)) * 512, row stride 512.
__global__ __launch_bounds__(256) void cvt_all(
    const float* __restrict__ x, unsigned short* __restrict__ Zbuf,
    unsigned short* __restrict__ Xbf)
{
    int idx = blockIdx.x * 256 + threadIdx.x;
    if (idx >= 131071 * 32) return;
    int row = idx >> 5, k = (idx & 31) * 8;
    const float* s = x + (size_t)row * 256 + k;
    unsigned short r[8];
#pragma unroll
    for (int i = 0; i < 8; i++) r[i] = f2bf(s[i]);
    unsigned short* dst;
    if (row < 65535) {
        int d = 31 - __clz(row + 1);
        int j = row - ((1 << d) - 1);
        dst = Zbuf + (size_t)(65536 - (2 << d)) * 512 + (size_t)j * 512 + k;
    } else {
        dst = Xbf + (size_t)(row - 65535) * 256 + k;
    }
    *(uint4*)dst = *(uint4*)r;
}

// ---------------- fused level kernel ----------------
// 512 threads = 8 waves. Tile: 64 nodes x NG*256 gate-cols, BK=32.
// LDS fragment-major: slot = ntile*64 + lane, 16 B per slot -> all ds ops
// lane-sequential (bank floor). Requires n multiple of 64 (true for n>=2048).
template<int NG>
__global__ __launch_bounds__(512) void fused_level(
    const unsigned short* __restrict__ Z, int Kdim,
    const unsigned short* __restrict__ W,
    const float* __restrict__ bias,
    const float* __restrict__ csrc,        // children c (2n x 256), null at leaf
    float* __restrict__ c_out,             // n x 256 fp32
    unsigned short* __restrict__ hs_out)   // parent Z base; write [p*512+256+h]
{
    constexpr int NTW = NG * 2;                       // n-tiles per wave
    constexpr int SMEM_STAGE = 4096 + NG * 16384;     // AsF + BsF bytes
    constexpr int SMEM_EPI   = NG * 16 * 264 * 4;
    constexpr int SMEM = SMEM_STAGE > SMEM_EPI ? SMEM_STAGE : SMEM_EPI;
    __shared__ __align__(16) char smem[SMEM];
    unsigned short* AsF = (unsigned short*)smem;          // 256 slots
    unsigned short* BsF = (unsigned short*)(smem + 4096); // NG*1024 slots
    float* Epi = (float*)smem;

    const int tid  = threadIdx.x;
    const int wave = tid >> 6, lane = tid & 63;
    const int bm   = blockIdx.x * 64;

    f32x4 acc[4][NTW] = {};

    // staging source pointers (16 B per lane, fragment-major gather)
    const unsigned short* aSrc =
        Z + (size_t)(bm + ((tid >> 6) & 3) * 16 + (lane & 15)) * Kdim + (lane >> 4) * 8;
    const unsigned short* bSrc[NTW];
#pragma unroll
    for (int p = 0; p < NTW; ++p) {
        int nt = p * 8 + wave;
        bSrc[p] = W + (size_t)(nt * 16 + (lane & 15)) * Kdim + (lane >> 4) * 8;
    }

    for (int k0 = 0; k0 < Kdim; k0 += 32) {
        if (tid < 256)
            *(uint4*)(AsF + tid * 8) = *(const uint4*)(aSrc + k0);
#pragma unroll
        for (int p = 0; p < NTW; ++p)
            *(uint4*)(BsF + (size_t)(p * 512 + tid) * 8) = *(const uint4*)(bSrc[p] + k0);
        __syncthreads();

        bf16x8 af[4];
#pragma unroll
        for (int i = 0; i < 4; ++i)
            af[i] = *(const bf16x8*)(AsF + (i * 64 + lane) * 8);
#pragma unroll
        for (int j = 0; j < NTW; ++j) {
            bf16x8 bfv = *(const bf16x8*)(BsF + (size_t)((wave * NTW + j) * 64 + lane) * 8);
#pragma unroll
            for (int i = 0; i < 4; ++i)
                acc[i][j] = __builtin_amdgcn_mfma_f32_16x16x32_bf16(af[i], bfv, acc[i][j], 0, 0, 0);
        }
        __syncthreads();
    }

    // ---- epilogue: 4 chunks of 16 rows through LDS ----
    const int cc = lane & 15, rq = (lane >> 4) * 4;
    for (int mt = 0; mt < 4; ++mt) {
        if (mt) __syncthreads();
#pragma unroll
        for (int j = 0; j < NTW; ++j) {
            int col = (wave * NTW + j) * 16 + cc;
            int g = col >> 8, h = col & 255;
#pragma unroll
            for (int r = 0; r < 4; ++r)
                Epi[(g * 16 + rq + r) * 264 + h] = acc[mt][j][r];
        }
        __syncthreads();
#pragma unroll
        for (int s = 0; s < 4; ++s) {
            int item = s * 512 + tid;
            int ploc = item >> 8, h = item & 255;
            int r0 = 2 * ploc;
            int node0 = bm + mt * 16 + r0;
            float b_i = bias[h], b_o = bias[256 + h], b_u = bias[512 + h];
            float i0 = sigf(Epi[(r0) * 264 + h] + b_i);
            float i1 = sigf(Epi[(r0 + 1) * 264 + h] + b_i);
            float o0 = sigf(Epi[(16 + r0) * 264 + h] + b_o);
            float o1 = sigf(Epi[(17 + r0) * 264 + h] + b_o);
            float u0 = tanhf(Epi[(32 + r0) * 264 + h] + b_u);
            float u1 = tanhf(Epi[(33 + r0) * 264 + h] + b_u);
            float c0 = i0 * u0, c1 = i1 * u1;
            if (NG == 5) {
                float b_f0 = bias[768 + h], b_f1 = bias[1024 + h];
                float f00 = sigf(Epi[(48 + r0) * 264 + h] + b_f0);
                float f01 = sigf(Epi[(49 + r0) * 264 + h] + b_f0);
                float f10 = sigf(Epi[(64 + r0) * 264 + h] + b_f1);
                float f11 = sigf(Epi[(65 + r0) * 264 + h] + b_f1);
                c0 += f00 * csrc[(size_t)(2 * node0) * 256 + h]
                    + f10 * csrc[(size_t)(2 * node0 + 1) * 256 + h];
                c1 += f01 * csrc[(size_t)(2 * node0 + 2) * 256 + h]
                    + f11 * csrc[(size_t)(2 * node0 + 3) * 256 + h];
            }
            float h0 = o0 * tanhf(c0), h1 = o1 * tanhf(c1);
            c_out[(size_t)node0 * 256 + h] = c0;
            c_out[(size_t)(node0 + 1) * 256 + h] = c1;
            hs_out[(size_t)(node0 >> 1) * 512 + 256 + h] = f2bf(h0 + h1);
        }
    }
}

// ---------------- bf16 MFMA NT-GEMM (small levels, writes pre) ----------------
__global__ __launch_bounds__(256) void gemm_bf16(
    const unsigned short* __restrict__ A, int lda, int M,
    const unsigned short* __restrict__ B, int ldb, int Kdim,
    const float* __restrict__ bias, float* __restrict__ C, int ldc)
{
    constexpr int LP = 72;
    __shared__ unsigned short As[128 * LP];
    __shared__ unsigned short Bs[128 * LP];

    const int tid  = threadIdx.x;
    const int wave = tid >> 6;
    const int lane = tid & 63;
    const int bm = blockIdx.x * 128;
    const int bn = blockIdx.y * 128;

    const int srow = tid >> 3;
    const int scol = (tid & 7) * 8;
    const int wm = (wave >> 1) * 64;
    const int wn = (wave & 1) * 64;
    const int lm = lane & 15;
    const int kq = (lane >> 4) * 8;

    f32x4 acc[4][4] = {};

    for (int k0 = 0; k0 < Kdim; k0 += 64) {
#pragma unroll
        for (int p = 0; p < 4; p++) {
            int r = srow + p * 32;
            int gr = bm + r;
            uint4 av = make_uint4(0u, 0u, 0u, 0u);
            if (gr < M) av = *(const uint4*)(A + (size_t)gr * lda + k0 + scol);
            *(uint4*)(As + r * LP + scol) = av;
            uint4 bv = *(const uint4*)(B + (size_t)(bn + r) * ldb + k0 + scol);
            *(uint4*)(Bs + r * LP + scol) = bv;
        }
        __syncthreads();

#pragma unroll
        for (int kk = 0; kk < 64; kk += 32) {
            bf16x8 af[4], bfr[4];
#pragma unroll
            for (int i = 0; i < 4; i++)
                af[i] = *(const bf16x8*)(As + (wm + i * 16 + lm) * LP + kk + kq);
#pragma unroll
            for (int j = 0; j < 4; j++)
                bfr[j] = *(const bf16x8*)(Bs + (wn + j * 16 + lm) * LP + kk + kq);
#pragma unroll
            for (int i = 0; i < 4; i++)
#pragma unroll
                for (int j = 0; j < 4; j++)
                    acc[i][j] = __builtin_amdgcn_mfma_f32_16x16x32_bf16(
                        af[i], bfr[j], acc[i][j], 0, 0, 0);
        }
        __syncthreads();
    }

    const int cr0 = (lane >> 4) * 4;
    const int ccc = lane & 15;
#pragma unroll
    for (int i = 0; i < 4; i++) {
#pragma unroll
        for (int reg = 0; reg < 4; reg++) {
            int r = bm + wm + i * 16 + cr0 + reg;
            if (r >= M) continue;
#pragma unroll
            for (int j = 0; j < 4; j++) {
                int cn = bn + wn + j * 16 + ccc;
                C[(size_t)r * ldc + cn] = acc[i][j][reg] + bias[cn];
            }
        }
    }
}

// ---------------- small-level epilogue (pre -> c, Hs; root -> out) ----------
__global__ __launch_bounds__(256) void epi_small(
    const float* __restrict__ pre, const float* __restrict__ csrc,
    float* __restrict__ c_out, unsigned short* __restrict__ hs_out,
    float* __restrict__ root_out, int npairs)
{
    int idx = blockIdx.x * 256 + threadIdx.x;
    if (root_out) {
        int h = idx;  // 256 threads
        const float* p = pre;
        float c = sigf(p[h]) * tanhf(p[512 + h])
                + sigf(p[768 + h]) * csrc[h]
                + sigf(p[1024 + h]) * csrc[256 + h];
        root_out[h] = sigf(p[256 + h]) * tanhf(c);
        root_out[256 + h] = c;
        return;
    }
    if (idx >= npairs * 256) return;
    int pI = idx >> 8, h = idx & 255;
    int n0 = 2 * pI;
    const float* p0 = pre + (size_t)n0 * 1280;
    const float* p1 = p0 + 1280;
    float c0 = sigf(p0[h]) * tanhf(p0[512 + h])
             + sigf(p0[768 + h]) * csrc[(size_t)(2 * n0) * 256 + h]
             + sigf(p0[1024 + h]) * csrc[(size_t)(2 * n0 + 1) * 256 + h];
    float c1 = sigf(p1[h]) * tanhf(p1[512 + h])
             + sigf(p1[768 + h]) * csrc[(size_t)(2 * n0 + 2) * 256 + h]
             + sigf(p1[1024 + h]) * csrc[(size_t)(2 * n0 + 3) * 256 + h];
    float h0 = sigf(p0[256 + h]) * tanhf(c0);
    float h1 = sigf(p1[256 + h]) * tanhf(c1);
    c_out[(size_t)n0 * 256 + h] = c0;
    c_out[(size_t)(n0 + 1) * 256 + h] = c1;
    hs_out[(size_t)pI * 512 + 256 + h] = f2bf(h0 + h1);
}

// ---------------- launch ----------------
extern "C" void kernel_launch(void* const* d_in, const int* in_sizes, int n_in,
                              void* d_out, int out_size, void* d_ws, size_t ws_size,
                              hipStream_t stream)
{
    const float* x   = (const float*)d_in[0];
    const float* Wi  = (const float*)d_in[1];
    const float* bi  = (const float*)d_in[2];
    const float* Wf  = (const float*)d_in[3];
    const float* bf  = (const float*)d_in[4];
    const float* Wo  = (const float*)d_in[5];
    const float* bo  = (const float*)d_in[6];
    const float* Wu  = (const float*)d_in[7];
    const float* bu  = (const float*)d_in[8];
    const float* Ui  = (const float*)d_in[9];
    const float* Uo  = (const float*)d_in[10];
    const float* Uu  = (const float*)d_in[11];
    const float* Wfk = (const float*)d_in[12];
    float* out = (float*)d_out;
    char* ws   = (char*)d_ws;
    (void)ws_size; (void)in_sizes; (void)n_in; (void)out_size;

    size_t off = 0;
    unsigned short* Wbig  = (unsigned short*)(ws + off); off += (size_t)1280 * 512 * 2;
    unsigned short* Wleaf = (unsigned short*)(ws + off); off += (size_t)768 * 256 * 2;
    float* bbig  = (float*)(ws + off); off += 1280 * 4;
    float* bleaf = (float*)(ws + off); off += 768 * 4 + 192;            // pad to 256B
    unsigned short* Xbf  = (unsigned short*)(ws + off); off += (size_t)65536 * 256 * 2;   // 32 MB
    unsigned short* Zbuf = (unsigned short*)(ws + off); off += (size_t)65536 * 512 * 2;   // 64 MB
    float* cA = (float*)(ws + off); off += (size_t)65536 * 256 * 4;     // 64 MB
    float* cB = (float*)(ws + off); off += (size_t)32768 * 256 * 4;     // 32 MB
    float* pre_small = (float*)(ws + off); off += (size_t)1024 * 1280 * 4;   // 5 MB

    auto zoffE = [](int d) -> size_t { return (size_t)(65536 - (2 << d)) * 512; };

    // 1) pack weights + one-shot x conversion (all levels)
    pack_weights<<<3336, 256, 0, stream>>>(Wi, bi, Wf, bf, Wo, bo, Wu, bu,
                                           Ui, Uo, Uu, Wfk, Wbig, Wleaf, bbig, bleaf);
    cvt_all<<<16384, 256, 0, stream>>>(x, Zbuf, Xbf);

    // 2) leaf: fused GEMM+epilogue -> cA, Hs into Z_15
    fused_level<3><<<LEAF_N / 64, 512, 0, stream>>>(
        Xbf, 256, Wleaf, bleaf, nullptr, cA, Zbuf + zoffE(15));

    // 3) internal levels, fused for n>=2048 (d>=11). src c = (d odd)?cA:cB.
    for (int d = 15; d >= 11; d--) {
        int n = 1 << d;
        float* csrc = (d & 1) ? cA : cB;
        float* cdst = (d & 1) ? cB : cA;
        fused_level<5><<<n / 64, 512, 0, stream>>>(
            Zbuf + zoffE(d), 512, Wbig, bbig, csrc, cdst, Zbuf + zoffE(d - 1));
    }

    // 4) small levels d=10..1: unfused gemm (pre in L2) + fused epilogue
    for (int d = 10; d >= 1; d--) {
        int n = 1 << d;
        float* csrc = (d & 1) ? cA : cB;
        float* cdst = (d & 1) ? cB : cA;
        gemm_bf16<<<dim3((n + 127) / 128, 10), 256, 0, stream>>>(
            Zbuf + zoffE(d), 512, n, Wbig, 512, 512, bbig, pre_small, 1280);
        epi_small<<<(n / 2 * 256 + 255) / 256, 256, 0, stream>>>(
            pre_small, csrc, cdst, Zbuf + zoffE(d - 1), nullptr, n / 2);
    }

    // 5) root d=0: gemm + epilogue straight to out = [h(256) | c(256)]
    gemm_bf16<<<dim3(1, 10), 256, 0, stream>>>(
        Zbuf + zoffE(0), 512, 1, Wbig, 512, 512, bbig, pre_small, 1280);
    epi_small<<<1, 256, 0, stream>>>(pre_small, cB, nullptr, nullptr, out, 0);
}

// Round 5
// 1152.762 us; speedup vs baseline: 2.7035x; 2.7035x over previous
//
#include <hip/hip_runtime.h>
#include <math.h>

// NaryTreeLSTM on MI355X — round 5: LDS-free fused GEMM+epilogue (round-4
// structure) + FIX: small-level (d<=3) Z regions padded to a full 16-row
// fragment tile. Round 4 overlapped them, so tail-level Hs writes trampled
// the next level's x (e.g. d=4's Hs at zoff(3)+4096.. = zoff(2)+0.. wiped
// level-2's x).
//
// Fragment layout:
//   frag(tile, kc) lane l, elem j <-> Mat[tile*16 + (l&15)][kc*32 + (l>>4)*8 + j]
//   flat addr = ((tile*KCN + kc)*64 + l)*8 + j    (KCN = K/32)
// C/D layout: row = (lane>>4)*4 + reg, col = lane&15.
// Wave w owns n-tiles {g*16 + 2w + t}, t=0,1 -> lane holds all gates at the
// same h -> fully in-register epilogue. acc statically indexed everywhere.

#define LEAF_N 65536

typedef __attribute__((ext_vector_type(8))) short bf16x8;
typedef __attribute__((ext_vector_type(4))) float f32x4;

__device__ __forceinline__ float sigf(float x) { return 1.0f / (1.0f + expf(-x)); }

__device__ __forceinline__ unsigned short f2bf(float f) {
    union { float f; unsigned u; } v; v.f = f;
    unsigned r = v.u + 0x7fffu + ((v.u >> 16) & 1u);   // RNE
    return (unsigned short)(r >> 16);
}

// Z region offset (elems). d>=4: packed back-to-back (n>=16, tile-aligned).
// d<=3: dedicated full tiles after the main area (8192 elems each).
__host__ __device__ __forceinline__ size_t zoffD(int d) {
    return (d >= 4) ? (size_t)(65536 - (2 << d)) * 512
                    : (size_t)65536 * 512 + (size_t)(3 - d) * 8192;
}

// ---------------- weight packing: fp32 -> bf16, fragment-major ----------------
// Wbig rows: [0:256)=[Wi|Ui],[256:512)=[Wo|Uo],[512:768)=[Wu|Uu],
//   [768:1024)=[Wf|Wfk0],[1024:1280)=[Wf|Wfk1]  (K=512)
// Wleaf rows: [Wi;Wo;Wu] (K=256)
__global__ __launch_bounds__(256) void pack_weights(
    const float* __restrict__ Wi, const float* __restrict__ bi,
    const float* __restrict__ Wf, const float* __restrict__ bf,
    const float* __restrict__ Wo, const float* __restrict__ bo,
    const float* __restrict__ Wu, const float* __restrict__ bu,
    const float* __restrict__ Ui, const float* __restrict__ Uo,
    const float* __restrict__ Uu, const float* __restrict__ Wfk,
    unsigned short* __restrict__ Wpk, unsigned short* __restrict__ WpkL,
    float* __restrict__ bbig, float* __restrict__ bleaf)
{
    int idx = blockIdx.x * 256 + threadIdx.x;
    const int NWB = 1280 * 512;   // 655360
    const int NWL = 768 * 256;    // 196608
    if (idx < NWB) {
        int j = idx & 7, l = (idx >> 3) & 63, kc = (idx >> 9) & 15, nt = idx >> 13;
        int row = nt * 16 + (l & 15);
        int k = kc * 32 + ((l >> 4) << 3) + j;
        int g = row >> 8, rr = row & 255;
        float v;
        if (k < 256) {
            const float* W = (g == 0) ? Wi : (g == 1) ? Wo : (g == 2) ? Wu : Wf;
            v = W[rr * 256 + k];
        } else {
            int kk = k - 256;
            v = (g == 0) ? Ui[rr * 256 + kk]
              : (g == 1) ? Uo[rr * 256 + kk]
              : (g == 2) ? Uu[rr * 256 + kk]
              : (g == 3) ? Wfk[rr * 256 + kk]
                         : Wfk[65536 + rr * 256 + kk];
        }
        Wpk[idx] = f2bf(v);
    } else if (idx < NWB + NWL) {
        int q = idx - NWB;
        int j = q & 7, l = (q >> 3) & 63, kc = (q >> 9) & 7, nt = q >> 12;
        int row = nt * 16 + (l & 15);
        int k = kc * 32 + ((l >> 4) << 3) + j;
        int g = row >> 8, rr = row & 255;
        const float* W = (g == 0) ? Wi : (g == 1) ? Wo : Wu;
        WpkL[q] = f2bf(W[rr * 256 + k]);
    } else if (idx < NWB + NWL + 1280) {
        int r = idx - NWB - NWL;
        int g = r >> 8, rr = r & 255;
        bbig[r] = (g == 0) ? bi[rr] : (g == 1) ? bo[rr] : (g == 2) ? bu[rr] : bf[rr];
    } else if (idx < NWB + NWL + 1280 + 768) {
        int r = idx - NWB - NWL - 1280;
        int g = r >> 8, rr = r & 255;
        bleaf[r] = (g == 0) ? bi[rr] : (g == 1) ? bo[rr] : bu[rr];
    }
}

// ---------------- x -> bf16, scattered into fragment-major Z / Xpk ----------
// Internal level region: [rt][kc:16][l:64][j:8]; x occupies kc 0..7.
// Leaf Xpk: [rt][kc:8][l:64][j:8].
__global__ __launch_bounds__(256) void cvt_all(
    const float* __restrict__ x, unsigned short* __restrict__ Zbuf,
    unsigned short* __restrict__ Xpk)
{
    int idx = blockIdx.x * 256 + threadIdx.x;
    if (idx >= 131071 * 32) return;
    int row = idx >> 5, k8 = idx & 31;            // k = k8*8 .. +7
    const float* s = x + (size_t)row * 256 + k8 * 8;
    unsigned short r[8];
#pragma unroll
    for (int i = 0; i < 8; i++) r[i] = f2bf(s[i]);
    int kc = k8 >> 2;                              // k/32 (0..7)
    if (row < 65535) {
        int d = 31 - __clz(row + 1);
        int jn = row - ((1 << d) - 1);
        int l = (jn & 15) + ((k8 & 3) << 4);
        size_t dst = zoffD(d) + ((size_t)((jn >> 4) * 16 + kc) * 64 + l) * 8;
        *(uint4*)(Zbuf + dst) = *(uint4*)r;
    } else {
        int jn = row - 65535;
        int l = (jn & 15) + ((k8 & 3) << 4);
        size_t dst = ((size_t)((jn >> 4) * 8 + kc) * 64 + l) * 8;
        *(uint4*)(Xpk + dst) = *(uint4*)r;
    }
}

// ---------------- fused level body ----------------
// 64 nodes starting at bm. NG=3 (leaf) / 5 (internal). KCN=K/32.
// GUARD: store-guard node<n (tail levels with n<64).
template<int NG, int KCN, bool GUARD>
__device__ __forceinline__ void level_body(
    const unsigned short* __restrict__ Zpk, const unsigned short* __restrict__ Wpk,
    const float* __restrict__ bias, const float* __restrict__ csrc,
    float* __restrict__ c_out, unsigned short* __restrict__ zparent,
    float* __restrict__ out, int bm, int n, bool is_root)
{
    const int tid = threadIdx.x, wave = tid >> 6, lane = tid & 63;
    const int cc = lane & 15, rq = (lane >> 4) * 4;

    f32x4 acc[4][2 * NG] = {};   // [mtile][g*2+t], all static indexing

    const unsigned short* aB = Zpk + ((size_t)(bm >> 4) * KCN * 64 + lane) * 8;
    const unsigned short* bB = Wpk + ((size_t)(2 * wave) * KCN * 64 + lane) * 8;

    for (int kc = 0; kc < KCN; ++kc) {
        bf16x8 af[4];
#pragma unroll
        for (int i = 0; i < 4; ++i)
            af[i] = *(const bf16x8*)(aB + (size_t)(i * KCN + kc) * 512);
#pragma unroll
        for (int g = 0; g < NG; ++g) {
#pragma unroll
            for (int t = 0; t < 2; ++t) {
                bf16x8 bv = *(const bf16x8*)(bB + (size_t)((g * 16 + t) * KCN + kc) * 512);
#pragma unroll
                for (int i = 0; i < 4; ++i)
                    acc[i][g * 2 + t] = __builtin_amdgcn_mfma_f32_16x16x32_bf16(
                        af[i], bv, acc[i][g * 2 + t], 0, 0, 0);
            }
        }
    }

    // ---- in-register epilogue ----
#pragma unroll
    for (int t = 0; t < 2; ++t) {
        const int h = (2 * wave + t) * 16 + cc;
        const float bI = bias[h], bO = bias[256 + h], bU = bias[512 + h];
        float bF0 = 0.f, bF1 = 0.f;
        if constexpr (NG == 5) { bF0 = bias[768 + h]; bF1 = bias[1024 + h]; }
#pragma unroll
        for (int mt = 0; mt < 4; ++mt) {
            const int node0 = bm + mt * 16 + rq;
            float hv[4];
#pragma unroll
            for (int r = 0; r < 4; ++r) {
                const int node = node0 + r;
                float iv = sigf(acc[mt][0 + t][r] + bI);
                float ov = sigf(acc[mt][2 + t][r] + bO);
                float uv = tanhf(acc[mt][4 + t][r] + bU);
                float cv = iv * uv;
                if constexpr (NG == 5) {
                    float f0 = sigf(acc[mt][6 + t][r] + bF0);
                    float f1 = sigf(acc[mt][8 + t][r] + bF1);
                    cv += f0 * csrc[(size_t)(2 * node) * 256 + h]
                        + f1 * csrc[(size_t)(2 * node + 1) * 256 + h];
                }
                if (!GUARD || node < n)
                    c_out[(size_t)node * 256 + h] = cv;
                hv[r] = ov * tanhf(cv);
                if (GUARD && is_root && node == 0) {
                    out[h] = hv[r];
                    out[256 + h] = cv;
                }
            }
            if (!is_root) {
#pragma unroll
                for (int pr = 0; pr < 2; ++pr) {
                    if (!GUARD || (node0 + 2 * pr) < n) {
                        const int p = (node0 >> 1) + pr;
                        // parent frag-major slot for col k=256+h (kc=8+(h>>5))
                        size_t a = ((size_t)((p >> 4) * 16 + 8 + (h >> 5)) * 64
                                    + (p & 15) + (((h >> 3) & 3) << 4)) * 8 + (h & 7);
                        zparent[a] = f2bf(hv[2 * pr] + hv[2 * pr + 1]);
                    }
                }
            }
        }
    }
}

// ---------------- big fused kernel (n multiple of 64) ----------------
template<int NG, int KCN>
__global__ __launch_bounds__(512, 2) void fused_level(
    const unsigned short* __restrict__ Zpk, const unsigned short* __restrict__ Wpk,
    const float* __restrict__ bias, const float* __restrict__ csrc,
    float* __restrict__ c_out, unsigned short* __restrict__ zparent)
{
    level_body<NG, KCN, false>(Zpk, Wpk, bias, csrc, c_out, zparent,
                               nullptr, blockIdx.x * 64, 1 << 30, false);
}

// ---------------- tail: levels d=5..0 in one single-block kernel ------------
__global__ __launch_bounds__(512, 2) void tail_levels(
    unsigned short* __restrict__ Zbuf, const unsigned short* __restrict__ Wpk,
    const float* __restrict__ bias, float* __restrict__ cA, float* __restrict__ cB,
    float* __restrict__ out)
{
    for (int d = 5; d >= 0; --d) {
        const int n = 1 << d;
        const unsigned short* Zpk = Zbuf + zoffD(d);
        unsigned short* zparent = Zbuf + zoffD(d > 0 ? d - 1 : 0); // unused at d=0
        const float* csrc = (d & 1) ? cA : cB;
        float* c_out = (d & 1) ? cB : cA;
        level_body<5, 16, true>(Zpk, Wpk, bias, csrc, c_out, zparent,
                                out, 0, n, d == 0);
        __syncthreads();
    }
}

// ---------------- launch ----------------
extern "C" void kernel_launch(void* const* d_in, const int* in_sizes, int n_in,
                              void* d_out, int out_size, void* d_ws, size_t ws_size,
                              hipStream_t stream)
{
    const float* x   = (const float*)d_in[0];
    const float* Wi  = (const float*)d_in[1];
    const float* bi  = (const float*)d_in[2];
    const float* Wf  = (const float*)d_in[3];
    const float* bf  = (const float*)d_in[4];
    const float* Wo  = (const float*)d_in[5];
    const float* bo  = (const float*)d_in[6];
    const float* Wu  = (const float*)d_in[7];
    const float* bu  = (const float*)d_in[8];
    const float* Ui  = (const float*)d_in[9];
    const float* Uo  = (const float*)d_in[10];
    const float* Uu  = (const float*)d_in[11];
    const float* Wfk = (const float*)d_in[12];
    float* out = (float*)d_out;
    char* ws   = (char*)d_ws;
    (void)ws_size; (void)in_sizes; (void)n_in; (void)out_size;

    size_t off = 0;
    unsigned short* Wpk  = (unsigned short*)(ws + off); off += (size_t)1280 * 512 * 2;
    unsigned short* WpkL = (unsigned short*)(ws + off); off += (size_t)768 * 256 * 2;
    float* bbig  = (float*)(ws + off); off += 1280 * 4;
    float* bleaf = (float*)(ws + off); off += 768 * 4 + 192;                 // 256B align
    unsigned short* Xpk  = (unsigned short*)(ws + off); off += (size_t)65536 * 256 * 2;        // 32 MB
    unsigned short* Zbuf = (unsigned short*)(ws + off); off += ((size_t)65536 * 512 + 32768) * 2; // 64 MB + pad tiles
    float* cA = (float*)(ws + off); off += (size_t)65536 * 256 * 4;          // 64 MB
    float* cB = (float*)(ws + off); off += (size_t)32768 * 256 * 4;          // 32 MB

    // 1) pack weights (frag-major bf16) + scatter x -> frag-major bf16
    pack_weights<<<3336, 256, 0, stream>>>(Wi, bi, Wf, bf, Wo, bo, Wu, bu,
                                           Ui, Uo, Uu, Wfk, Wpk, WpkL, bbig, bleaf);
    cvt_all<<<16385, 256, 0, stream>>>(x, Zbuf, Xpk);

    // 2) leaf: fused -> cA, Hs into Z_15
    fused_level<3, 8><<<LEAF_N / 64, 512, 0, stream>>>(
        Xpk, WpkL, bleaf, nullptr, cA, Zbuf + zoffD(15));

    // 3) internal levels d=15..6 fused (n multiple of 64)
    for (int d = 15; d >= 6; d--) {
        float* csrc = (d & 1) ? cA : cB;
        float* cdst = (d & 1) ? cB : cA;
        fused_level<5, 16><<<1 << (d - 6), 512, 0, stream>>>(
            Zbuf + zoffD(d), Wpk, bbig, csrc, cdst, Zbuf + zoffD(d - 1));
    }

    // 4) tail d=5..0 (63 nodes) in one block; writes out = [h(256)|c(256)]
    tail_levels<<<1, 512, 0, stream>>>(Zbuf, Wpk, bbig, cA, cB, out);
}

// Round 6
// 963.000 us; speedup vs baseline: 3.2362x; 1.1971x over previous
//
#include <hip/hip_runtime.h>
#include <math.h>

// NaryTreeLSTM on MI355X — round 6: fused kernel with 32-node tiles (acc=80
// regs/lane, half of round 5's 160 which starved the scheduler of VGPRs and
// serialized every load -> 50us single-wave chains), explicit register
// double-buffering of fragment loads, and gate-parallel small levels
// (round-5's single-block tail_levels was 294us of pure load latency).
//
// Fragment layout:
//   frag(tile, kc) lane l, elem j <-> Mat[tile*16 + (l&15)][kc*32 + (l>>4)*8 + j]
//   flat addr = ((tile*KCN + kc)*64 + l)*8 + j    (KCN = K/32)
// C/D layout: row = (lane>>4)*4 + reg, col = lane&15.

#define LEAF_N 65536

typedef __attribute__((ext_vector_type(8))) short bf16x8;
typedef __attribute__((ext_vector_type(4))) float f32x4;

__device__ __forceinline__ float sigf(float x) { return 1.0f / (1.0f + expf(-x)); }

__device__ __forceinline__ unsigned short f2bf(float f) {
    union { float f; unsigned u; } v; v.f = f;
    unsigned r = v.u + 0x7fffu + ((v.u >> 16) & 1u);   // RNE
    return (unsigned short)(r >> 16);
}

// Z region offset (elems). d>=4: packed back-to-back (tile-aligned).
// d<=3: dedicated full 16-row tiles after the main area (8192 elems each).
__host__ __device__ __forceinline__ size_t zoffD(int d) {
    return (d >= 4) ? (size_t)(65536 - (2 << d)) * 512
                    : (size_t)65536 * 512 + (size_t)(3 - d) * 8192;
}

// ---------------- weight packing: fp32 -> bf16, fragment-major ----------------
// Wbig rows: [0:256)=[Wi|Ui],[256:512)=[Wo|Uo],[512:768)=[Wu|Uu],
//   [768:1024)=[Wf|Wfk0],[1024:1280)=[Wf|Wfk1]  (K=512)
// Wleaf rows: [Wi;Wo;Wu] (K=256)
__global__ __launch_bounds__(256) void pack_weights(
    const float* __restrict__ Wi, const float* __restrict__ bi,
    const float* __restrict__ Wf, const float* __restrict__ bf,
    const float* __restrict__ Wo, const float* __restrict__ bo,
    const float* __restrict__ Wu, const float* __restrict__ bu,
    const float* __restrict__ Ui, const float* __restrict__ Uo,
    const float* __restrict__ Uu, const float* __restrict__ Wfk,
    unsigned short* __restrict__ Wpk, unsigned short* __restrict__ WpkL,
    float* __restrict__ bbig, float* __restrict__ bleaf)
{
    int idx = blockIdx.x * 256 + threadIdx.x;
    const int NWB = 1280 * 512;   // 655360
    const int NWL = 768 * 256;    // 196608
    if (idx < NWB) {
        int j = idx & 7, l = (idx >> 3) & 63, kc = (idx >> 9) & 15, nt = idx >> 13;
        int row = nt * 16 + (l & 15);
        int k = kc * 32 + ((l >> 4) << 3) + j;
        int g = row >> 8, rr = row & 255;
        float v;
        if (k < 256) {
            const float* W = (g == 0) ? Wi : (g == 1) ? Wo : (g == 2) ? Wu : Wf;
            v = W[rr * 256 + k];
        } else {
            int kk = k - 256;
            v = (g == 0) ? Ui[rr * 256 + kk]
              : (g == 1) ? Uo[rr * 256 + kk]
              : (g == 2) ? Uu[rr * 256 + kk]
              : (g == 3) ? Wfk[rr * 256 + kk]
                         : Wfk[65536 + rr * 256 + kk];
        }
        Wpk[idx] = f2bf(v);
    } else if (idx < NWB + NWL) {
        int q = idx - NWB;
        int j = q & 7, l = (q >> 3) & 63, kc = (q >> 9) & 7, nt = q >> 12;
        int row = nt * 16 + (l & 15);
        int k = kc * 32 + ((l >> 4) << 3) + j;
        int g = row >> 8, rr = row & 255;
        const float* W = (g == 0) ? Wi : (g == 1) ? Wo : Wu;
        WpkL[q] = f2bf(W[rr * 256 + k]);
    } else if (idx < NWB + NWL + 1280) {
        int r = idx - NWB - NWL;
        int g = r >> 8, rr = r & 255;
        bbig[r] = (g == 0) ? bi[rr] : (g == 1) ? bo[rr] : (g == 2) ? bu[rr] : bf[rr];
    } else if (idx < NWB + NWL + 1280 + 768) {
        int r = idx - NWB - NWL - 1280;
        int g = r >> 8, rr = r & 255;
        bleaf[r] = (g == 0) ? bi[rr] : (g == 1) ? bo[rr] : bu[rr];
    }
}

// ---------------- x -> bf16, scattered into fragment-major Z / Xpk ----------
__global__ __launch_bounds__(256) void cvt_all(
    const float* __restrict__ x, unsigned short* __restrict__ Zbuf,
    unsigned short* __restrict__ Xpk)
{
    int idx = blockIdx.x * 256 + threadIdx.x;
    if (idx >= 131071 * 32) return;
    int row = idx >> 5, k8 = idx & 31;
    const float* s = x + (size_t)row * 256 + k8 * 8;
    unsigned short r[8];
#pragma unroll
    for (int i = 0; i < 8; i++) r[i] = f2bf(s[i]);
    int kc = k8 >> 2;                              // k/32 (0..7)
    if (row < 65535) {
        int d = 31 - __clz(row + 1);
        int jn = row - ((1 << d) - 1);
        int l = (jn & 15) + ((k8 & 3) << 4);
        size_t dst = zoffD(d) + ((size_t)((jn >> 4) * 16 + kc) * 64 + l) * 8;
        *(uint4*)(Zbuf + dst) = *(uint4*)r;
    } else {
        int jn = row - 65535;
        int l = (jn & 15) + ((k8 & 3) << 4);
        size_t dst = ((size_t)((jn >> 4) * 8 + kc) * 64 + l) * 8;
        *(uint4*)(Xpk + dst) = *(uint4*)r;
    }
}

// ---------------- fused level kernel: 32 nodes x all gates ----------------
// 512 thr = 8 waves; wave owns n-tiles {g*16 + 2*wave + t}, t=0,1.
// acc[2][2*NG]: mtile x (g*2+t). Register double-buffered fragment loads.
template<int NG, int KCN>
__global__ __launch_bounds__(512, 2) void fused_level(
    const unsigned short* __restrict__ Zpk, const unsigned short* __restrict__ Wpk,
    const float* __restrict__ bias, const float* __restrict__ csrc,
    float* __restrict__ c_out, unsigned short* __restrict__ zparent,
    int leaf_flag)
{
    const int tid = threadIdx.x, wave = tid >> 6, lane = tid & 63;
    const int bm = blockIdx.x * 32;
    const int cc = lane & 15, rq = (lane >> 4) * 4;

    f32x4 acc[2][2 * NG] = {};

    const unsigned short* aB = Zpk + ((size_t)(bm >> 4) * KCN * 64 + lane) * 8;
    const unsigned short* bB = Wpk + ((size_t)(2 * wave) * KCN * 64 + lane) * 8;

    bf16x8 afX[2], bvX[2 * NG];      // buffer A (even kc)
    bf16x8 afY[2], bvY[2 * NG];      // buffer B (odd kc)

#pragma unroll
    for (int i = 0; i < 2; ++i)
        afX[i] = *(const bf16x8*)(aB + (size_t)(i * KCN) * 512);
#pragma unroll
    for (int g = 0; g < NG; ++g)
#pragma unroll
        for (int t = 0; t < 2; ++t)
            bvX[g * 2 + t] = *(const bf16x8*)(bB + (size_t)((g * 16 + t) * KCN) * 512);

    auto do_mfma = [&](bf16x8 (&af)[2], bf16x8 (&bv)[2 * NG]) {
#pragma unroll
        for (int g = 0; g < NG; ++g)
#pragma unroll
            for (int t = 0; t < 2; ++t)
#pragma unroll
                for (int i = 0; i < 2; ++i)
                    acc[i][g * 2 + t] = __builtin_amdgcn_mfma_f32_16x16x32_bf16(
                        af[i], bv[g * 2 + t], acc[i][g * 2 + t], 0, 0, 0);
    };

#pragma unroll
    for (int kc = 0; kc < KCN; kc += 2) {
        // issue loads for kc+1 into Y
#pragma unroll
        for (int i = 0; i < 2; ++i)
            afY[i] = *(const bf16x8*)(aB + (size_t)(i * KCN + kc + 1) * 512);
#pragma unroll
        for (int g = 0; g < NG; ++g)
#pragma unroll
            for (int t = 0; t < 2; ++t)
                bvY[g * 2 + t] = *(const bf16x8*)(bB + (size_t)((g * 16 + t) * KCN + kc + 1) * 512);
        do_mfma(afX, bvX);                  // consume kc (X)
        if (kc + 2 < KCN) {                 // issue loads for kc+2 into X
#pragma unroll
            for (int i = 0; i < 2; ++i)
                afX[i] = *(const bf16x8*)(aB + (size_t)(i * KCN + kc + 2) * 512);
#pragma unroll
            for (int g = 0; g < NG; ++g)
#pragma unroll
                for (int t = 0; t < 2; ++t)
                    bvX[g * 2 + t] = *(const bf16x8*)(bB + (size_t)((g * 16 + t) * KCN + kc + 2) * 512);
        }
        do_mfma(afY, bvY);                  // consume kc+1 (Y)
    }

    // ---- in-register epilogue ----
#pragma unroll
    for (int t = 0; t < 2; ++t) {
        const int h = (2 * wave + t) * 16 + cc;
        const float bI = bias[h], bO = bias[256 + h], bU = bias[512 + h];
        float bF0 = 0.f, bF1 = 0.f;
        if constexpr (NG == 5) { bF0 = bias[768 + h]; bF1 = bias[1024 + h]; }
#pragma unroll
        for (int mt = 0; mt < 2; ++mt) {
            const int node0 = bm + mt * 16 + rq;
            float hv[4];
#pragma unroll
            for (int r = 0; r < 4; ++r) {
                const int node = node0 + r;
                float iv = sigf(acc[mt][0 + t][r] + bI);
                float ov = sigf(acc[mt][2 + t][r] + bO);
                float uv = tanhf(acc[mt][4 + t][r] + bU);
                float cv = iv * uv;
                if constexpr (NG == 5) {
                    float f0 = sigf(acc[mt][6 + t][r] + bF0);
                    float f1 = sigf(acc[mt][8 + t][r] + bF1);
                    cv += f0 * csrc[(size_t)(2 * node) * 256 + h]
                        + f1 * csrc[(size_t)(2 * node + 1) * 256 + h];
                }
                c_out[(size_t)node * 256 + h] = cv;
                hv[r] = ov * tanhf(cv);
            }
#pragma unroll
            for (int pr = 0; pr < 2; ++pr) {
                const int p = ((node0 + 2 * pr) >> 1);
                size_t a = ((size_t)((p >> 4) * 16 + 8 + (h >> 5)) * 64
                            + (p & 15) + (((h >> 3) & 3) << 4)) * 8 + (h & 7);
                zparent[a] = f2bf(hv[2 * pr] + hv[2 * pr + 1]);
            }
        }
    }
    (void)leaf_flag;
}

// ---------------- small levels (n<=16): gate-parallel GEMM -> pre ----------
// grid = 20 one-wave blocks: block q computes rows 0..15 x cols
// (q/4)*256 + (q%4)*64 + j*16 + cc  (j<4). Writes pre (bias added). KCN=16.
__global__ __launch_bounds__(64) void small_gemm(
    const unsigned short* __restrict__ Zpk, const unsigned short* __restrict__ Wpk,
    const float* __restrict__ bias, float* __restrict__ pre, int n)
{
    const int lane = threadIdx.x;
    const int q = blockIdx.x;
    const int nt0 = (q >> 2) * 16 + (q & 3) * 4;
    const int cc = lane & 15, rq = (lane >> 4) * 4;

    f32x4 acc[4] = {};
    const unsigned short* aB = Zpk + (size_t)lane * 8;
    const unsigned short* bB = Wpk + ((size_t)nt0 * 16 * 64 + lane) * 8;

    bf16x8 aX, bX[4], aY, bY[4];
    aX = *(const bf16x8*)(aB);
#pragma unroll
    for (int j = 0; j < 4; ++j)
        bX[j] = *(const bf16x8*)(bB + (size_t)(j * 16) * 512);

#pragma unroll
    for (int kc = 0; kc < 16; kc += 2) {
        aY = *(const bf16x8*)(aB + (size_t)(kc + 1) * 512);
#pragma unroll
        for (int j = 0; j < 4; ++j)
            bY[j] = *(const bf16x8*)(bB + (size_t)(j * 16 + kc + 1) * 512);
#pragma unroll
        for (int j = 0; j < 4; ++j)
            acc[j] = __builtin_amdgcn_mfma_f32_16x16x32_bf16(aX, bX[j], acc[j], 0, 0, 0);
        if (kc + 2 < 16) {
            aX = *(const bf16x8*)(aB + (size_t)(kc + 2) * 512);
#pragma unroll
            for (int j = 0; j < 4; ++j)
                bX[j] = *(const bf16x8*)(bB + (size_t)(j * 16 + kc + 2) * 512);
        }
#pragma unroll
        for (int j = 0; j < 4; ++j)
            acc[j] = __builtin_amdgcn_mfma_f32_16x16x32_bf16(aY, bY[j], acc[j], 0, 0, 0);
    }

#pragma unroll
    for (int j = 0; j < 4; ++j) {
        int coln = (nt0 + j) * 16 + cc;
        float bb = bias[coln];
#pragma unroll
        for (int r = 0; r < 4; ++r) {
            int row = rq + r;
            if (row < n) pre[(size_t)row * 1280 + coln] = acc[j][r] + bb;
        }
    }
}

// ---------------- small-level epilogue (pre -> c, Hs; root -> out) ----------
__global__ __launch_bounds__(256) void epi_small(
    const float* __restrict__ pre, const float* __restrict__ csrc,
    float* __restrict__ c_out, unsigned short* __restrict__ zparent,
    float* __restrict__ root_out, int npairs)
{
    int idx = blockIdx.x * 256 + threadIdx.x;
    if (root_out) {
        int h = idx;  // 256 threads
        const float* p = pre;
        float c = sigf(p[h]) * tanhf(p[512 + h])
                + sigf(p[768 + h]) * csrc[h]
                + sigf(p[1024 + h]) * csrc[256 + h];
        root_out[h] = sigf(p[256 + h]) * tanhf(c);
        root_out[256 + h] = c;
        return;
    }
    if (idx >= npairs * 256) return;
    int pI = idx >> 8, h = idx & 255;
    int n0 = 2 * pI;
    const float* p0 = pre + (size_t)n0 * 1280;
    const float* p1 = p0 + 1280;
    float c0 = sigf(p0[h]) * tanhf(p0[512 + h])
             + sigf(p0[768 + h]) * csrc[(size_t)(2 * n0) * 256 + h]
             + sigf(p0[1024 + h]) * csrc[(size_t)(2 * n0 + 1) * 256 + h];
    float c1 = sigf(p1[h]) * tanhf(p1[512 + h])
             + sigf(p1[768 + h]) * csrc[(size_t)(2 * n0 + 2) * 256 + h]
             + sigf(p1[1024 + h]) * csrc[(size_t)(2 * n0 + 3) * 256 + h];
    float h0 = sigf(p0[256 + h]) * tanhf(c0);
    float h1 = sigf(p1[256 + h]) * tanhf(c1);
    c_out[(size_t)n0 * 256 + h] = c0;
    c_out[(size_t)(n0 + 1) * 256 + h] = c1;
    size_t a = ((size_t)((pI >> 4) * 16 + 8 + (h >> 5)) * 64
                + (pI & 15) + (((h >> 3) & 3) << 4)) * 8 + (h & 7);
    zparent[a] = f2bf(h0 + h1);
}

// ---------------- launch ----------------
extern "C" void kernel_launch(void* const* d_in, const int* in_sizes, int n_in,
                              void* d_out, int out_size, void* d_ws, size_t ws_size,
                              hipStream_t stream)
{
    const float* x   = (const float*)d_in[0];
    const float* Wi  = (const float*)d_in[1];
    const float* bi  = (const float*)d_in[2];
    const float* Wf  = (const float*)d_in[3];
    const float* bf  = (const float*)d_in[4];
    const float* Wo  = (const float*)d_in[5];
    const float* bo  = (const float*)d_in[6];
    const float* Wu  = (const float*)d_in[7];
    const float* bu  = (const float*)d_in[8];
    const float* Ui  = (const float*)d_in[9];
    const float* Uo  = (const float*)d_in[10];
    const float* Uu  = (const float*)d_in[11];
    const float* Wfk = (const float*)d_in[12];
    float* out = (float*)d_out;
    char* ws   = (char*)d_ws;
    (void)ws_size; (void)in_sizes; (void)n_in; (void)out_size;

    size_t off = 0;
    unsigned short* Wpk  = (unsigned short*)(ws + off); off += (size_t)1280 * 512 * 2;
    unsigned short* WpkL = (unsigned short*)(ws + off); off += (size_t)768 * 256 * 2;
    float* bbig  = (float*)(ws + off); off += 1280 * 4;
    float* bleaf = (float*)(ws + off); off += 768 * 4 + 192;                 // 256B align
    unsigned short* Xpk  = (unsigned short*)(ws + off); off += (size_t)65536 * 256 * 2;
    unsigned short* Zbuf = (unsigned short*)(ws + off); off += ((size_t)65536 * 512 + 32768) * 2;
    float* cA = (float*)(ws + off); off += (size_t)65536 * 256 * 4;
    float* cB = (float*)(ws + off); off += (size_t)32768 * 256 * 4;
    float* pre_small = (float*)(ws + off); off += (size_t)16 * 1280 * 4;

    // 1) pack weights (frag-major bf16) + scatter x -> frag-major bf16
    pack_weights<<<3336, 256, 0, stream>>>(Wi, bi, Wf, bf, Wo, bo, Wu, bu,
                                           Ui, Uo, Uu, Wfk, Wpk, WpkL, bbig, bleaf);
    cvt_all<<<16385, 256, 0, stream>>>(x, Zbuf, Xpk);

    // 2) leaf: fused -> cA, Hs into Z_15
    fused_level<3, 8><<<LEAF_N / 32, 512, 0, stream>>>(
        Xpk, WpkL, bleaf, nullptr, cA, Zbuf + zoffD(15), 1);

    // 3) internal levels d=15..5 fused (n multiple of 32)
    for (int d = 15; d >= 5; d--) {
        float* csrc = (d & 1) ? cA : cB;
        float* cdst = (d & 1) ? cB : cA;
        fused_level<5, 16><<<1 << (d - 5), 512, 0, stream>>>(
            Zbuf + zoffD(d), Wpk, bbig, csrc, cdst, Zbuf + zoffD(d - 1), 0);
    }

    // 4) small levels d=4..1: gate-parallel gemm (pre in L2) + epilogue
    for (int d = 4; d >= 1; d--) {
        int n = 1 << d;
        float* csrc = (d & 1) ? cA : cB;
        float* cdst = (d & 1) ? cB : cA;
        small_gemm<<<20, 64, 0, stream>>>(Zbuf + zoffD(d), Wpk, bbig, pre_small, n);
        epi_small<<<n / 2, 256, 0, stream>>>(pre_small, csrc, cdst,
                                             Zbuf + zoffD(d - 1), nullptr, n / 2);
    }

    // 5) root: gemm + epilogue straight to out = [h(256)|c(256)]
    small_gemm<<<20, 64, 0, stream>>>(Zbuf + zoffD(0), Wpk, bbig, pre_small, 1);
    epi_small<<<1, 256, 0, stream>>>(pre_small, cB, nullptr, nullptr, out, 0);
}